// Round 6
// baseline (422.657 us; speedup 1.0000x reference)
//
#include <hip/hip_runtime.h>

typedef __attribute__((ext_vector_type(8))) short short8;   // 8 bf16
typedef __attribute__((ext_vector_type(4))) float f32x4;    // MFMA acc

__device__ __forceinline__ unsigned short bf16r(float f) {
  unsigned int u = __float_as_uint(f);
  u = (u + 0x7FFFu + ((u >> 16) & 1u)) >> 16;
  return (unsigned short)u;
}
__device__ __forceinline__ float bf2f(unsigned short h) {
  return __uint_as_float(((unsigned int)h) << 16);
}
__device__ __forceinline__ unsigned int pk2(float a, float b) {
  return (unsigned int)bf16r(a) | ((unsigned int)bf16r(b) << 16);
}

// async 16B global->LDS (dest is wave-uniform base + lane*16)
__device__ __forceinline__ void gload16(const unsigned short* g, unsigned short* l) {
  __builtin_amdgcn_global_load_lds(
      (const __attribute__((address_space(1))) unsigned int*)g,
      (__attribute__((address_space(3))) unsigned int*)l, 16, 0, 0);
}

// Stage a 128x32 bf16 tile (8KB) into LDS, XOR-swizzled chunks.
__device__ __forceinline__ void stage_tile(const unsigned short* __restrict__ gsrc, int ld,
                                           int k0, unsigned short* Ls, int t) {
  const int w = t >> 6;
  const int o0 = t * 16;
  const int r0 = o0 >> 6;
  const int c0 = ((((o0 >> 4) & 3) ^ ((r0 >> 2) & 3)) << 3);
  const int r1 = r0 + 64;
  const int c1 = ((((o0 >> 4) & 3) ^ ((r1 >> 2) & 3)) << 3);
  gload16(gsrc + (long)r0 * ld + k0 + c0, Ls + w * 512);
  gload16(gsrc + (long)r1 * ld + k0 + c1, Ls + 2048 + w * 512);
}

// Double-buffered LDS K-loop (2-phase), 128x128 tile, 4 waves, 4x4 frags.
__device__ __forceinline__ void kloop(const unsigned short* __restrict__ A,
                                      const unsigned short* __restrict__ B,
                                      int lda, int ldb, int K,
                                      unsigned short* As, unsigned short* Bs,  // [2][4096]
                                      int t, f32x4 acc[4][4]) {
  const int lane = t & 63;
  const int w = t >> 6;
  const int wr = w >> 1, wc = w & 1;
  const int ra = lane & 15;
  const int ch = ((lane >> 4) ^ (ra >> 2)) << 3;
  stage_tile(A, lda, 0, As, t);
  stage_tile(B, ldb, 0, Bs, t);
  __syncthreads();
  for (int k0 = 0; k0 < K; k0 += 32) {
    const int p = (k0 >> 5) & 1;
    unsigned short* Ac = As + p * 4096;
    unsigned short* Bc = Bs + p * 4096;
    if (k0 + 32 < K) {
      stage_tile(A, lda, k0 + 32, As + (p ^ 1) * 4096, t);
      stage_tile(B, ldb, k0 + 32, Bs + (p ^ 1) * 4096, t);
    }
    short8 a[4], b[4];
#pragma unroll
    for (int i = 0; i < 4; ++i)
      a[i] = *(const short8*)(Ac + (wr * 64 + i * 16 + ra) * 32 + ch);
#pragma unroll
    for (int j = 0; j < 4; ++j)
      b[j] = *(const short8*)(Bc + (wc * 64 + j * 16 + ra) * 32 + ch);
#pragma unroll
    for (int i = 0; i < 4; ++i)
#pragma unroll
      for (int j = 0; j < 4; ++j)
        acc[i][j] = __builtin_amdgcn_mfma_f32_16x16x32_bf16(b[j], a[i], acc[i][j], 0, 0, 0);
    __syncthreads();
  }
}

// ---------------- fused fp32->bf16 convert of all inputs ----------------
__global__ __launch_bounds__(256)
void cvt_all(const float* __restrict__ ref, const float* __restrict__ sup,
             const float* __restrict__ fcw, const float* __restrict__ wq,
             const float* __restrict__ wk, const float* __restrict__ wv,
             unsigned short* __restrict__ Xb, unsigned short* __restrict__ FCW,
             unsigned short* __restrict__ WQB, unsigned short* __restrict__ WKB,
             unsigned short* __restrict__ WVB) {
  long u = ((long)blockIdx.x * 256 + threadIdx.x) * 4;
  const float* src; unsigned short* dst;
  if (u < 2097152)      { src = ref + u;             dst = Xb + u; }
  else if (u < 3145728) { src = sup + (u - 2097152); dst = Xb + u; }
  else if (u < 4194304) { src = fcw + (u - 3145728); dst = FCW + (u - 3145728); }
  else if (u < 5242880) { src = wq + (u - 4194304);  dst = WQB + (u - 4194304); }
  else if (u < 6291456) { src = wk + (u - 5242880);  dst = WKB + (u - 5242880); }
  else                  { src = wv + (u - 6291456);  dst = WVB + (u - 6291456); }
  float4 v = *(const float4*)src;
  ushort4 o;
  o.x = bf16r(v.x); o.y = bf16r(v.y); o.z = bf16r(v.z); o.w = bf16r(v.w);
  *(ushort4*)dst = o;
}

// ---------------- fc: RS = relu(X @ fcW^T + b), bf16 out ----------------
__global__ __launch_bounds__(256)
void gemm_fc(const unsigned short* __restrict__ X, const unsigned short* __restrict__ W,
             const float* __restrict__ bias, unsigned short* __restrict__ RS) {
  __shared__ unsigned short As[8192], Bs[8192];
  const int t = threadIdx.x, lane = t & 63, w = t >> 6;
  const int wr = w >> 1, wc = w & 1;
  const int row0 = blockIdx.x * 128, col0 = blockIdx.y * 128;
  f32x4 acc[4][4] = {};
  kloop(X + (long)row0 * 1024, W + (long)col0 * 1024, 1024, 1024, 1024, As, Bs, t, acc);
  const int rl = lane & 15, q4 = (lane >> 4) << 2;
#pragma unroll
  for (int i = 0; i < 4; ++i) {
    int rr = row0 + wr * 64 + i * 16 + rl;
#pragma unroll
    for (int j = 0; j < 4; ++j) {
      int cc = col0 + wc * 64 + j * 16 + q4;
      float4 bb = *(const float4*)(bias + cc);
      float v0 = fmaxf(acc[i][j][0] + bb.x, 0.f);
      float v1 = fmaxf(acc[i][j][1] + bb.y, 0.f);
      float v2 = fmaxf(acc[i][j][2] + bb.z, 0.f);
      float v3 = fmaxf(acc[i][j][3] + bb.w, 0.f);
      uint2 o; o.x = pk2(v0, v1); o.y = pk2(v2, v3);
      *(uint2*)(RS + (long)rr * 1024 + cc) = o;
    }
  }
}

// ---------------- batched Q/K/SV: z=0 Q, z=1 K, z=2 SV^T ----------------
__global__ __launch_bounds__(256)
void gemm_qkv(const unsigned short* __restrict__ RS,
              const unsigned short* __restrict__ WQ, const unsigned short* __restrict__ WK,
              const unsigned short* __restrict__ WV,
              const float* __restrict__ qb, const float* __restrict__ kb,
              unsigned short* __restrict__ QG, unsigned short* __restrict__ KG,
              unsigned short* __restrict__ SVT) {
  const int z = blockIdx.z;
  const unsigned short* A; const unsigned short* B; int M;
  if (z == 0)      { A = RS;           B = WQ; M = 2048; }
  else if (z == 1) { A = RS + 2097152; B = WK; M = 1024; }
  else             { A = RS + 2097152; B = WV; M = 1024; }
  const int row0 = blockIdx.x * 128;
  if (row0 >= M) return;
  const int col0 = blockIdx.y * 128;
  __shared__ unsigned short As[8192], Bs[8192];
  const int t = threadIdx.x, lane = t & 63, w = t >> 6;
  const int wr = w >> 1, wc = w & 1;
  f32x4 acc[4][4] = {};
  kloop(A + (long)row0 * 1024, B + (long)col0 * 1024, 1024, 1024, 1024, As, Bs, t, acc);
  const int rl = lane & 15, q4 = (lane >> 4) << 2;
  if (z == 2) {
#pragma unroll
    for (int i = 0; i < 4; ++i) {
      int rr = row0 + wr * 64 + i * 16 + rl;           // sup row = SVT col
#pragma unroll
      for (int j = 0; j < 4; ++j) {
        int cg = col0 + wc * 64 + j * 16 + q4;         // output channel
#pragma unroll
        for (int ri = 0; ri < 4; ++ri) {
          int gg = (cg + ri) >> 6, jj = (cg + ri) & 63;
          SVT[(long)gg * 65536 + (long)jj * 1024 + rr] = bf16r(acc[i][j][ri]);
        }
      }
    }
  } else {
    const float* bias = z ? kb : qb;
    unsigned short* out = z ? KG : QG;
    const long gs = z ? 65536 : 131072;
#pragma unroll
    for (int i = 0; i < 4; ++i) {
      int rr = row0 + wr * 64 + i * 16 + rl;
#pragma unroll
      for (int j = 0; j < 4; ++j) {
        int cc = col0 + wc * 64 + j * 16 + q4;
        float4 bb = *(const float4*)(bias + cc);
        int gg = cc >> 6, jj = cc & 63;
        uint2 o;
        o.x = pk2(acc[i][j][0] + bb.x, acc[i][j][1] + bb.y);
        o.y = pk2(acc[i][j][2] + bb.z, acc[i][j][3] + bb.w);
        *(uint2*)(out + (long)gg * gs + (long)rr * 64 + jj) = o;
      }
    }
  }
}

// ---------------- fused conv(E->G) + scores + softmax + PV + epilogue ----
// Block = 16 n-rows, 512 threads (8 waves), wave w owns groups {2w, 2w+1}.
// m streamed in 64-chunks with online softmax; pe staged via global_load_lds
// in 8-e-slice double-buffered groups. Layout invariant: scores-MFMA C-layout
// (n=lane&15, m=16*mb+4*hi+ri) == conv accumulator layout.
__global__ __launch_bounds__(512)
void pe_attn(const float* __restrict__ pe, const float* __restrict__ wgw,
             const float* __restrict__ wgb,
             const unsigned short* __restrict__ QG,
             const unsigned short* __restrict__ KG,
             const unsigned short* __restrict__ SVT,
             const unsigned short* __restrict__ RS,
             const float* __restrict__ wvb, float* __restrict__ out)
{
  __shared__ __align__(16) unsigned char peb[2][32768];  // 8 slices x [16n][64m] f32, swz
  __shared__ __align__(16) unsigned char Qs[32768];      // [16n][16g][64d] bf16, swz
  __shared__ __align__(16) unsigned char Ps[8][2048];    // per-wave [16n][64m] bf16, swz
  __shared__ float wgs[1024];                            // [64e][16g]

  const int t = threadIdx.x;
  const int lane = t & 63;
  const int w = t >> 6;
  const int n0 = blockIdx.x * 16;
  const int rl = lane & 15;
  const int hi = lane >> 4;
  const int g0 = w * 2;
  const float C2 = 0.18033688011112042f;  // log2(e)/8

  // wg: wgw[g][e] -> wgs[e*16+g]
  for (int i = t; i < 1024; i += 512) wgs[(i & 63) * 16 + (i >> 6)] = wgw[i];
  // Q: QG[g][n0+r][d] -> Qs[(r*2048 + g*128 + sg*16) ^ ((r&7)<<4)]
  for (int u = t; u < 2048; u += 512) {
    int r = u >> 7, rem = u & 127, g = rem >> 3, sg = rem & 7;
    short8 q = *(const short8*)(QG + (long)g * 131072 + (long)(n0 + r) * 64 + sg * 8);
    *(short8*)(Qs + ((r * 2048 + g * 128 + sg * 16) ^ ((r & 7) << 4))) = q;
  }

  auto STAGE = [&](int cg2) {
    const int buf = cg2 & 1;
    const int e = (cg2 & 7) * 8 + w;
    const int m0s = (cg2 >> 3) * 64;
#pragma unroll
    for (int q = 0; q < 4; ++q) {
      int r = 4 * q + hi;
      int sp = (lane & 15) ^ (r & 3) ^ (((r >> 2) & 1) << 2);
      gload16((const unsigned short*)(pe + (long)e * 2097152 + (long)(n0 + r) * 1024 + m0s + sp * 4),
              (unsigned short*)(&peb[buf][w * 4096 + q * 1024 + lane * 16]));
    }
  };

  STAGE(0);

  f32x4 Oa[2][4] = {};
  float mx0 = -1e30f, mx1 = -1e30f, sm0 = 0.f, sm1 = 0.f;
  const float bias0 = wgb[g0], bias1 = wgb[g0 + 1];
  unsigned char* Pw = Ps[w];
  const int rowsw = rl * 256;                       // pe-LDS row base
  const int cmsk = ((rl & 3) << 4) ^ (((rl >> 2) & 1) << 6);  // pe-LDS col swz
  const int qmsk = (rl & 7) << 4;                   // Q/P LDS swz

  int cg = 0;
  for (int chunk = 0; chunk < 16; ++chunk) {
    const int m0 = chunk * 64;
    f32x4 conv[2][4];
#pragma unroll
    for (int mb = 0; mb < 4; ++mb) {
      conv[0][mb] = (f32x4){bias0, bias0, bias0, bias0};
      conv[1][mb] = (f32x4){bias1, bias1, bias1, bias1};
    }
    // ---- conv accumulation over E, 8 slices per group, dbuf ----
    for (int grp = 0; grp < 8; ++grp, ++cg) {
      __syncthreads();                       // group cg staged; prev compute done
      if (cg + 1 < 128) STAGE(cg + 1);
      const unsigned char* pb = peb[cg & 1];
      const int ebase = (cg & 7) * 8;
#pragma unroll
      for (int ii = 0; ii < 8; ++ii) {
        float wg0 = wgs[(ebase + ii) * 16 + g0];
        float wg1 = wgs[(ebase + ii) * 16 + g0 + 1];
#pragma unroll
        for (int mb = 0; mb < 4; ++mb) {
          f32x4 p = *(const f32x4*)(pb + ii * 4096 + rowsw + ((mb * 64 + hi * 16) ^ cmsk));
          conv[0][mb] += p * wg0;
          conv[1][mb] += p * wg1;
        }
      }
    }
    // ---- scores: s = (Q K^T), C-layout matches conv ----
    f32x4 sa[2][4];
#pragma unroll
    for (int gi = 0; gi < 2; ++gi) {
      const int g = g0 + gi;
#pragma unroll
      for (int mb = 0; mb < 4; ++mb) {
        f32x4 z = {};
#pragma unroll
        for (int kc = 0; kc < 2; ++kc) {
          short8 kf = *(const short8*)(KG + (long)g * 65536 +
                                       (long)(m0 + mb * 16 + rl) * 64 + kc * 32 + hi * 8);
          short8 qf = *(const short8*)(Qs + ((rl * 2048 + g * 128 + (kc * 32 + hi * 8) * 2) ^ qmsk));
          z = __builtin_amdgcn_mfma_f32_16x16x32_bf16(kf, qf, z, 0, 0, 0);
        }
        sa[gi][mb] = z;
      }
    }
    // ---- per-group: combine, online softmax, P->LDS, PV ----
#pragma unroll
    for (int gi = 0; gi < 2; ++gi) {
      const int g = g0 + gi;
      float wv[4][4];
      float cmax = -1e30f;
#pragma unroll
      for (int mb = 0; mb < 4; ++mb)
#pragma unroll
        for (int ri = 0; ri < 4; ++ri) {
          float v = __builtin_amdgcn_logf(fmaxf(conv[gi][mb][ri], 0.f) + 1e-6f)
                  + sa[gi][mb][ri] * C2;
          wv[mb][ri] = v;
          cmax = fmaxf(cmax, v);
        }
      cmax = fmaxf(cmax, __shfl_xor(cmax, 16));
      cmax = fmaxf(cmax, __shfl_xor(cmax, 32));
      float oldm = gi ? mx1 : mx0;
      float newm = fmaxf(oldm, cmax);
      float scale = __builtin_amdgcn_exp2f(oldm - newm);
      float csum = 0.f;
      float pv[4][4];
#pragma unroll
      for (int mb = 0; mb < 4; ++mb)
#pragma unroll
        for (int ri = 0; ri < 4; ++ri) {
          float p = __builtin_amdgcn_exp2f(wv[mb][ri] - newm);
          pv[mb][ri] = p;
          csum += p;
        }
      csum += __shfl_xor(csum, 16);
      csum += __shfl_xor(csum, 32);
      if (gi) { mx1 = newm; sm1 = sm1 * scale + csum; }
      else    { mx0 = newm; sm0 = sm0 * scale + csum; }
#pragma unroll
      for (int jb = 0; jb < 4; ++jb) Oa[gi][jb] *= scale;
      // pack P (bf16) into wave-private LDS, swizzled
#pragma unroll
      for (int mb = 0; mb < 4; ++mb) {
        uint2 o;
        o.x = pk2(pv[mb][0], pv[mb][1]);
        o.y = pk2(pv[mb][2], pv[mb][3]);
        *(uint2*)(Pw + ((rl * 128 + mb * 32 + hi * 8) ^ qmsk)) = o;
      }
      // PV: Oa += SV_frag x P_frag
#pragma unroll
      for (int jb = 0; jb < 4; ++jb) {
#pragma unroll
        for (int mc = 0; mc < 2; ++mc) {
          short8 sv = *(const short8*)(SVT + (long)g * 65536 +
                                       (long)(jb * 16 + rl) * 1024 + m0 + mc * 32 + hi * 8);
          short8 pf = *(const short8*)(Pw + ((rl * 128 + mc * 64 + hi * 16) ^ qmsk));
          Oa[gi][jb] = __builtin_amdgcn_mfma_f32_16x16x32_bf16(sv, pf, Oa[gi][jb], 0, 0, 0);
        }
      }
    }
  }
  // ---- epilogue: out = O/sum + wv_b + R ----
  const int n = n0 + rl;
#pragma unroll
  for (int gi = 0; gi < 2; ++gi) {
    float rs = __builtin_amdgcn_rcpf(gi ? sm1 : sm0);
#pragma unroll
    for (int jb = 0; jb < 4; ++jb) {
      int oc = (g0 + gi) * 64 + jb * 16 + hi * 4;
      float4 wb = *(const float4*)(wvb + oc);
      ushort4 r4 = *(const ushort4*)(RS + (long)n * 1024 + oc);
      float4 o;
      o.x = Oa[gi][jb][0] * rs + wb.x + bf2f(r4.x);
      o.y = Oa[gi][jb][1] * rs + wb.y + bf2f(r4.y);
      o.z = Oa[gi][jb][2] * rs + wb.z + bf2f(r4.z);
      o.w = Oa[gi][jb][3] * rs + wb.w + bf2f(r4.w);
      *(float4*)(out + (long)n * 1024 + oc) = o;
    }
  }
}

extern "C" void kernel_launch(void* const* d_in, const int* in_sizes, int n_in,
                              void* d_out, int out_size, void* d_ws, size_t ws_size,
                              hipStream_t stream) {
  const float* ref_feat = (const float*)d_in[0];
  const float* sup_feat = (const float*)d_in[1];
  const float* pe       = (const float*)d_in[2];
  const float* fc_w     = (const float*)d_in[3];
  const float* fc_b     = (const float*)d_in[4];
  const float* wg_w     = (const float*)d_in[5];
  const float* wg_b     = (const float*)d_in[6];
  const float* wq_w     = (const float*)d_in[7];
  const float* wq_b     = (const float*)d_in[8];
  const float* wk_w     = (const float*)d_in[9];
  const float* wk_b     = (const float*)d_in[10];
  const float* wv_w     = (const float*)d_in[11];
  const float* wv_b     = (const float*)d_in[12];

  char* ws = (char*)d_ws;
  unsigned short* Xb  = (unsigned short*)(ws);              // [3072][1024]
  unsigned short* FCW = (unsigned short*)(ws + 6291456);
  unsigned short* WQB = (unsigned short*)(ws + 8388608);
  unsigned short* WKB = (unsigned short*)(ws + 10485760);
  unsigned short* WVB = (unsigned short*)(ws + 12582912);
  unsigned short* RS  = (unsigned short*)(ws + 14680064);   // [3072][1024] relu(fc) bf16
  unsigned short* QG  = (unsigned short*)(ws + 20971520);   // [16][2048][64]
  unsigned short* KG  = (unsigned short*)(ws + 25165824);   // [16][1024][64]
  unsigned short* SVT = (unsigned short*)(ws + 27262976);   // [16][64][1024]

  cvt_all<<<7168, 256, 0, stream>>>(ref_feat, sup_feat, fc_w, wq_w, wk_w, wv_w,
                                    Xb, FCW, WQB, WKB, WVB);
  gemm_fc<<<dim3(24, 8), 256, 0, stream>>>(Xb, FCW, fc_b, RS);
  gemm_qkv<<<dim3(16, 8, 3), 256, 0, stream>>>(RS, WQB, WKB, WVB, wq_b, wk_b, QG, KG, SVT);
  pe_attn<<<128, 512, 0, stream>>>(pe, wg_w, wg_b, QG, KG, SVT, RS, wv_b, (float*)d_out);
}

// Round 7
// 301.536 us; speedup vs baseline: 1.4017x; 1.4017x over previous
//
#include <hip/hip_runtime.h>

typedef __attribute__((ext_vector_type(8))) short short8;   // 8 bf16
typedef __attribute__((ext_vector_type(4))) float f32x4;    // MFMA acc

__device__ __forceinline__ unsigned short bf16r(float f) {
  unsigned int u = __float_as_uint(f);
  u = (u + 0x7FFFu + ((u >> 16) & 1u)) >> 16;
  return (unsigned short)u;
}
__device__ __forceinline__ float bf2f(unsigned short h) {
  return __uint_as_float(((unsigned int)h) << 16);
}
__device__ __forceinline__ unsigned int pk2(float a, float b) {
  return (unsigned int)bf16r(a) | ((unsigned int)bf16r(b) << 16);
}

// async 16B global->LDS (dest is wave-uniform base + lane*16)
__device__ __forceinline__ void gload16(const unsigned short* g, unsigned short* l) {
  __builtin_amdgcn_global_load_lds(
      (const __attribute__((address_space(1))) unsigned int*)g,
      (__attribute__((address_space(3))) unsigned int*)l, 16, 0, 0);
}

// Stage a 128x32 bf16 tile (8KB) into LDS, XOR-swizzled chunks.
__device__ __forceinline__ void stage_tile(const unsigned short* __restrict__ gsrc, int ld,
                                           int k0, unsigned short* Ls, int t) {
  const int w = t >> 6;
  const int o0 = t * 16;
  const int r0 = o0 >> 6;
  const int c0 = ((((o0 >> 4) & 3) ^ ((r0 >> 2) & 3)) << 3);
  const int r1 = r0 + 64;
  const int c1 = ((((o0 >> 4) & 3) ^ ((r1 >> 2) & 3)) << 3);
  gload16(gsrc + (long)r0 * ld + k0 + c0, Ls + w * 512);
  gload16(gsrc + (long)r1 * ld + k0 + c1, Ls + 2048 + w * 512);
}

// Double-buffered LDS K-loop (2-phase), 128x128 tile, 4 waves, 4x4 frags.
__device__ __forceinline__ void kloop(const unsigned short* __restrict__ A,
                                      const unsigned short* __restrict__ B,
                                      int lda, int ldb, int K,
                                      unsigned short* As, unsigned short* Bs,  // [2][4096]
                                      int t, f32x4 acc[4][4]) {
  const int lane = t & 63;
  const int w = t >> 6;
  const int wr = w >> 1, wc = w & 1;
  const int ra = lane & 15;
  const int ch = ((lane >> 4) ^ (ra >> 2)) << 3;
  stage_tile(A, lda, 0, As, t);
  stage_tile(B, ldb, 0, Bs, t);
  __syncthreads();
  for (int k0 = 0; k0 < K; k0 += 32) {
    const int p = (k0 >> 5) & 1;
    unsigned short* Ac = As + p * 4096;
    unsigned short* Bc = Bs + p * 4096;
    if (k0 + 32 < K) {
      stage_tile(A, lda, k0 + 32, As + (p ^ 1) * 4096, t);
      stage_tile(B, ldb, k0 + 32, Bs + (p ^ 1) * 4096, t);
    }
    short8 a[4], b[4];
#pragma unroll
    for (int i = 0; i < 4; ++i)
      a[i] = *(const short8*)(Ac + (wr * 64 + i * 16 + ra) * 32 + ch);
#pragma unroll
    for (int j = 0; j < 4; ++j)
      b[j] = *(const short8*)(Bc + (wc * 64 + j * 16 + ra) * 32 + ch);
#pragma unroll
    for (int i = 0; i < 4; ++i)
#pragma unroll
      for (int j = 0; j < 4; ++j)
        acc[i][j] = __builtin_amdgcn_mfma_f32_16x16x32_bf16(b[j], a[i], acc[i][j], 0, 0, 0);
    __syncthreads();
  }
}

// ---------------- fused fp32->bf16 convert of all inputs ----------------
__global__ __launch_bounds__(256)
void cvt_all(const float* __restrict__ ref, const float* __restrict__ sup,
             const float* __restrict__ fcw, const float* __restrict__ wq,
             const float* __restrict__ wk, const float* __restrict__ wv,
             unsigned short* __restrict__ Xb, unsigned short* __restrict__ FCW,
             unsigned short* __restrict__ WQB, unsigned short* __restrict__ WKB,
             unsigned short* __restrict__ WVB) {
  long u = ((long)blockIdx.x * 256 + threadIdx.x) * 4;
  const float* src; unsigned short* dst;
  if (u < 2097152)      { src = ref + u;             dst = Xb + u; }
  else if (u < 3145728) { src = sup + (u - 2097152); dst = Xb + u; }
  else if (u < 4194304) { src = fcw + (u - 3145728); dst = FCW + (u - 3145728); }
  else if (u < 5242880) { src = wq + (u - 4194304);  dst = WQB + (u - 4194304); }
  else if (u < 6291456) { src = wk + (u - 5242880);  dst = WKB + (u - 5242880); }
  else                  { src = wv + (u - 6291456);  dst = WVB + (u - 6291456); }
  float4 v = *(const float4*)src;
  ushort4 o;
  o.x = bf16r(v.x); o.y = bf16r(v.y); o.z = bf16r(v.z); o.w = bf16r(v.w);
  *(ushort4*)dst = o;
}

// ---------------- fc: RS = relu(X @ fcW^T + b), bf16 out ----------------
__global__ __launch_bounds__(256)
void gemm_fc(const unsigned short* __restrict__ X, const unsigned short* __restrict__ W,
             const float* __restrict__ bias, unsigned short* __restrict__ RS) {
  __shared__ unsigned short As[8192], Bs[8192];
  const int t = threadIdx.x, lane = t & 63, w = t >> 6;
  const int wr = w >> 1, wc = w & 1;
  const int row0 = blockIdx.x * 128, col0 = blockIdx.y * 128;
  f32x4 acc[4][4] = {};
  kloop(X + (long)row0 * 1024, W + (long)col0 * 1024, 1024, 1024, 1024, As, Bs, t, acc);
  const int rl = lane & 15, q4 = (lane >> 4) << 2;
#pragma unroll
  for (int i = 0; i < 4; ++i) {
    int rr = row0 + wr * 64 + i * 16 + rl;
#pragma unroll
    for (int j = 0; j < 4; ++j) {
      int cc = col0 + wc * 64 + j * 16 + q4;
      float4 bb = *(const float4*)(bias + cc);
      float v0 = fmaxf(acc[i][j][0] + bb.x, 0.f);
      float v1 = fmaxf(acc[i][j][1] + bb.y, 0.f);
      float v2 = fmaxf(acc[i][j][2] + bb.z, 0.f);
      float v3 = fmaxf(acc[i][j][3] + bb.w, 0.f);
      uint2 o; o.x = pk2(v0, v1); o.y = pk2(v2, v3);
      *(uint2*)(RS + (long)rr * 1024 + cc) = o;
    }
  }
}

// ---------------- batched Q/K/SV: z=0 Q, z=1 K, z=2 SV^T ----------------
__global__ __launch_bounds__(256)
void gemm_qkv(const unsigned short* __restrict__ RS,
              const unsigned short* __restrict__ WQ, const unsigned short* __restrict__ WK,
              const unsigned short* __restrict__ WV,
              const float* __restrict__ qb, const float* __restrict__ kb,
              unsigned short* __restrict__ QG, unsigned short* __restrict__ KG,
              unsigned short* __restrict__ SVT) {
  const int z = blockIdx.z;
  const unsigned short* A; const unsigned short* B; int M;
  if (z == 0)      { A = RS;           B = WQ; M = 2048; }
  else if (z == 1) { A = RS + 2097152; B = WK; M = 1024; }
  else             { A = RS + 2097152; B = WV; M = 1024; }
  const int row0 = blockIdx.x * 128;
  if (row0 >= M) return;
  const int col0 = blockIdx.y * 128;
  __shared__ unsigned short As[8192], Bs[8192];
  const int t = threadIdx.x, lane = t & 63, w = t >> 6;
  const int wr = w >> 1, wc = w & 1;
  f32x4 acc[4][4] = {};
  kloop(A + (long)row0 * 1024, B + (long)col0 * 1024, 1024, 1024, 1024, As, Bs, t, acc);
  const int rl = lane & 15, q4 = (lane >> 4) << 2;
  if (z == 2) {
#pragma unroll
    for (int i = 0; i < 4; ++i) {
      int rr = row0 + wr * 64 + i * 16 + rl;           // sup row = SVT col
#pragma unroll
      for (int j = 0; j < 4; ++j) {
        int cg = col0 + wc * 64 + j * 16 + q4;         // output channel
#pragma unroll
        for (int ri = 0; ri < 4; ++ri) {
          int gg = (cg + ri) >> 6, jj = (cg + ri) & 63;
          SVT[(long)gg * 65536 + (long)jj * 1024 + rr] = bf16r(acc[i][j][ri]);
        }
      }
    }
  } else {
    const float* bias = z ? kb : qb;
    unsigned short* out = z ? KG : QG;
    const long gs = z ? 65536 : 131072;
#pragma unroll
    for (int i = 0; i < 4; ++i) {
      int rr = row0 + wr * 64 + i * 16 + rl;
#pragma unroll
      for (int j = 0; j < 4; ++j) {
        int cc = col0 + wc * 64 + j * 16 + q4;
        float4 bb = *(const float4*)(bias + cc);
        int gg = cc >> 6, jj = cc & 63;
        uint2 o;
        o.x = pk2(acc[i][j][0] + bb.x, acc[i][j][1] + bb.y);
        o.y = pk2(acc[i][j][2] + bb.z, acc[i][j][3] + bb.w);
        *(uint2*)(out + (long)gg * gs + (long)rr * 64 + jj) = o;
      }
    }
  }
}

// ------- fused conv(E->G) + scores + partial softmax + PV (m-split x4) -----
// Grid (128, 4): block = 16 n-rows x 256 m. 8 waves, wave w owns groups
// {2w, 2w+1}. pe staged in 4-e-slice double-buffered groups (16 KB).
// Writes UNNORMALIZED partial O + per-(n,g) (max,sum) for the combine pass.
__global__ __launch_bounds__(512)
void pe_attn2(const float* __restrict__ pe, const float* __restrict__ wgw,
              const float* __restrict__ wgb,
              const unsigned short* __restrict__ QG,
              const unsigned short* __restrict__ KG,
              const unsigned short* __restrict__ SVT,
              float* __restrict__ Opart, float* __restrict__ ms)
{
  __shared__ __align__(16) unsigned char peb[2][16384];  // 4 slices x [16n][64m] f32 swz
  __shared__ __align__(16) unsigned char Ps[8][2048];    // per-wave [16n][64m] bf16 swz
  __shared__ float wgs[1024];                            // [64e][16g]

  const int t = threadIdx.x;
  const int lane = t & 63;
  const int w = t >> 6;
  const int n0 = blockIdx.x * 16;
  const int sp = blockIdx.y;
  const int mbase = sp * 256;
  const int rl = lane & 15;
  const int hi = lane >> 4;
  const int g0 = w * 2;
  const float C2 = 0.18033688011112042f;  // log2(e)/8

  for (int i = t; i < 1024; i += 512) wgs[(i & 63) * 16 + (i >> 6)] = wgw[i];

  // Q fragments in registers: qf[gi][kc] = Q[n=rl][d = kc*32 + hi*8 ..+7]
  short8 qf0k0 = *(const short8*)(QG + (long)g0 * 131072 + (long)(n0 + rl) * 64 + hi * 8);
  short8 qf0k1 = *(const short8*)(QG + (long)g0 * 131072 + (long)(n0 + rl) * 64 + 32 + hi * 8);
  short8 qf1k0 = *(const short8*)(QG + (long)(g0 + 1) * 131072 + (long)(n0 + rl) * 64 + hi * 8);
  short8 qf1k1 = *(const short8*)(QG + (long)(g0 + 1) * 131072 + (long)(n0 + rl) * 64 + 32 + hi * 8);

  // STAGE group cg (4 e-slices x 16n x 64m): wave pair (w&1) covers 8 rows,
  // slice = w>>1. LDS linear dest; source pre-swizzled col = 4*((lane&15)^(r&7)).
  auto STAGE = [&](int cg2) {
    const int buf = cg2 & 1;
    const int e = (cg2 & 15) * 4 + (w >> 1);
    const int m0s = mbase + (cg2 >> 4) * 64;
#pragma unroll
    for (int q = 0; q < 2; ++q) {
      int r = (w & 1) * 8 + q * 4 + hi;
      gload16((const unsigned short*)(pe + (long)e * 2097152 + (long)(n0 + r) * 1024 +
                                      m0s + 4 * ((lane & 15) ^ (r & 7))),
              (unsigned short*)(&peb[buf][(w >> 1) * 4096 + ((w & 1) * 8 + q * 4) * 256 + lane * 16]));
    }
  };

  STAGE(0);

  f32x4 Oa[2][4] = {};
  float mx0 = -1e30f, mx1 = -1e30f, sm0 = 0.f, sm1 = 0.f;
  const float bias0 = wgb[g0], bias1 = wgb[g0 + 1];
  unsigned char* Pw = Ps[w];
  const int qmsk = (rl & 7) << 4;

  int cg = 0;
  for (int chunk = 0; chunk < 4; ++chunk) {
    const int m0c = mbase + chunk * 64;
    f32x4 conv[2][4];
#pragma unroll
    for (int mb = 0; mb < 4; ++mb) {
      conv[0][mb] = (f32x4){bias0, bias0, bias0, bias0};
      conv[1][mb] = (f32x4){bias1, bias1, bias1, bias1};
    }
    // ---- conv over E: 16 groups of 4 slices, double-buffered ----
    for (int grp = 0; grp < 16; ++grp, ++cg) {
      __syncthreads();                       // group cg resident
      if (cg + 1 < 64) STAGE(cg + 1);
      const unsigned char* pb = peb[cg & 1];
      const int ebase = (cg & 15) * 4;
#pragma unroll
      for (int ii = 0; ii < 4; ++ii) {
        float wg0 = wgs[(ebase + ii) * 16 + g0];
        float wg1 = wgs[(ebase + ii) * 16 + g0 + 1];
#pragma unroll
        for (int mb = 0; mb < 4; ++mb) {
          f32x4 p = *(const f32x4*)(pb + ii * 4096 + rl * 256 + ((mb * 64 + hi * 16) ^ qmsk));
          conv[0][mb] += p * wg0;
          conv[1][mb] += p * wg1;
        }
      }
    }
    // ---- scores: C[m][n] layout == conv layout (m=16mb+4hi+ri, n=rl) ----
    f32x4 sa[2][4];
#pragma unroll
    for (int mb = 0; mb < 4; ++mb) {
      const long krow = (long)(m0c + mb * 16 + rl) * 64 + hi * 8;
      short8 kf0a = *(const short8*)(KG + (long)g0 * 65536 + krow);
      short8 kf0b = *(const short8*)(KG + (long)g0 * 65536 + krow + 32);
      short8 kf1a = *(const short8*)(KG + (long)(g0 + 1) * 65536 + krow);
      short8 kf1b = *(const short8*)(KG + (long)(g0 + 1) * 65536 + krow + 32);
      f32x4 z0 = {}, z1 = {};
      z0 = __builtin_amdgcn_mfma_f32_16x16x32_bf16(kf0a, qf0k0, z0, 0, 0, 0);
      z0 = __builtin_amdgcn_mfma_f32_16x16x32_bf16(kf0b, qf0k1, z0, 0, 0, 0);
      z1 = __builtin_amdgcn_mfma_f32_16x16x32_bf16(kf1a, qf1k0, z1, 0, 0, 0);
      z1 = __builtin_amdgcn_mfma_f32_16x16x32_bf16(kf1b, qf1k1, z1, 0, 0, 0);
      sa[0][mb] = z0;
      sa[1][mb] = z1;
    }
    // ---- per-group: logits, online softmax, P->LDS, PV ----
#pragma unroll
    for (int gi = 0; gi < 2; ++gi) {
      const int g = g0 + gi;
      float wv[4][4];
      float cmax = -1e30f;
#pragma unroll
      for (int mb = 0; mb < 4; ++mb)
#pragma unroll
        for (int ri = 0; ri < 4; ++ri) {
          float v = __builtin_amdgcn_logf(fmaxf(conv[gi][mb][ri], 0.f) + 1e-6f)
                  + sa[gi][mb][ri] * C2;
          wv[mb][ri] = v;
          cmax = fmaxf(cmax, v);
        }
      cmax = fmaxf(cmax, __shfl_xor(cmax, 16));
      cmax = fmaxf(cmax, __shfl_xor(cmax, 32));
      float oldm = gi ? mx1 : mx0;
      float newm = fmaxf(oldm, cmax);
      float scale = __builtin_amdgcn_exp2f(oldm - newm);
      float csum = 0.f;
      float pv[4][4];
#pragma unroll
      for (int mb = 0; mb < 4; ++mb)
#pragma unroll
        for (int ri = 0; ri < 4; ++ri) {
          float p = __builtin_amdgcn_exp2f(wv[mb][ri] - newm);
          pv[mb][ri] = p;
          csum += p;
        }
      csum += __shfl_xor(csum, 16);
      csum += __shfl_xor(csum, 32);
      if (gi) { mx1 = newm; sm1 = sm1 * scale + csum; }
      else    { mx0 = newm; sm0 = sm0 * scale + csum; }
#pragma unroll
      for (int jb = 0; jb < 4; ++jb) Oa[gi][jb] *= scale;
#pragma unroll
      for (int mb = 0; mb < 4; ++mb) {
        uint2 o;
        o.x = pk2(pv[mb][0], pv[mb][1]);
        o.y = pk2(pv[mb][2], pv[mb][3]);
        *(uint2*)(Pw + ((rl * 128 + mb * 32 + hi * 8) ^ qmsk)) = o;
      }
#pragma unroll
      for (int jb = 0; jb < 4; ++jb) {
#pragma unroll
        for (int mc = 0; mc < 2; ++mc) {
          short8 sv = *(const short8*)(SVT + (long)g * 65536 +
                                       (long)(jb * 16 + rl) * 1024 + m0c + mc * 32 + hi * 8);
          short8 pf = *(const short8*)(Pw + ((rl * 128 + mc * 64 + hi * 16) ^ qmsk));
          Oa[gi][jb] = __builtin_amdgcn_mfma_f32_16x16x32_bf16(sv, pf, Oa[gi][jb], 0, 0, 0);
        }
      }
    }
  }
  // ---- write partials: Opart[sp][n][g*64+d] (unnormalized), ms[sp][n][g] ----
  const int n = n0 + rl;
#pragma unroll
  for (int gi = 0; gi < 2; ++gi) {
    if (hi == 0) {
      float2 v; v.x = gi ? mx1 : mx0; v.y = gi ? sm1 : sm0;
      *(float2*)(ms + (((long)sp * 2048 + n) * 16 + g0 + gi) * 2) = v;
    }
#pragma unroll
    for (int jb = 0; jb < 4; ++jb) {
      *(f32x4*)(Opart + ((long)sp * 2048 + n) * 1024 + (g0 + gi) * 64 + jb * 16 + hi * 4) =
          Oa[gi][jb];
    }
  }
}

// ---------------- combine m-splits + epilogue: out = O/S + wv_b + R ----------
__global__ __launch_bounds__(256)
void combine(const float* __restrict__ Opart, const float* __restrict__ ms,
             const unsigned short* __restrict__ RS, const float* __restrict__ wvb,
             float* __restrict__ out) {
  const int n = blockIdx.x;
  const int t = threadIdx.x;
  const int g = t >> 4;
  float mv0, mv1, mv2, mv3, sv0, sv1, sv2, sv3;
  {
    float2 a = *(const float2*)(ms + (((long)0 * 2048 + n) * 16 + g) * 2);
    float2 b = *(const float2*)(ms + (((long)1 * 2048 + n) * 16 + g) * 2);
    float2 c = *(const float2*)(ms + (((long)2 * 2048 + n) * 16 + g) * 2);
    float2 d = *(const float2*)(ms + (((long)3 * 2048 + n) * 16 + g) * 2);
    mv0 = a.x; sv0 = a.y; mv1 = b.x; sv1 = b.y;
    mv2 = c.x; sv2 = c.y; mv3 = d.x; sv3 = d.y;
  }
  float M = fmaxf(fmaxf(mv0, mv1), fmaxf(mv2, mv3));
  float w0 = __builtin_amdgcn_exp2f(mv0 - M);
  float w1 = __builtin_amdgcn_exp2f(mv1 - M);
  float w2 = __builtin_amdgcn_exp2f(mv2 - M);
  float w3 = __builtin_amdgcn_exp2f(mv3 - M);
  float S = sv0 * w0 + sv1 * w1 + sv2 * w2 + sv3 * w3;
  f32x4 acc;
  acc  = (*(const f32x4*)(Opart + ((long)0 * 2048 + n) * 1024 + t * 4)) * w0;
  acc += (*(const f32x4*)(Opart + ((long)1 * 2048 + n) * 1024 + t * 4)) * w1;
  acc += (*(const f32x4*)(Opart + ((long)2 * 2048 + n) * 1024 + t * 4)) * w2;
  acc += (*(const f32x4*)(Opart + ((long)3 * 2048 + n) * 1024 + t * 4)) * w3;
  float rs = __builtin_amdgcn_rcpf(S);
  const int oc = t * 4;
  float4 wb = *(const float4*)(wvb + oc);
  ushort4 r4 = *(const ushort4*)(RS + (long)n * 1024 + oc);
  float4 o;
  o.x = acc[0] * rs + wb.x + bf2f(r4.x);
  o.y = acc[1] * rs + wb.y + bf2f(r4.y);
  o.z = acc[2] * rs + wb.z + bf2f(r4.z);
  o.w = acc[3] * rs + wb.w + bf2f(r4.w);
  *(float4*)(out + (long)n * 1024 + oc) = o;
}

extern "C" void kernel_launch(void* const* d_in, const int* in_sizes, int n_in,
                              void* d_out, int out_size, void* d_ws, size_t ws_size,
                              hipStream_t stream) {
  const float* ref_feat = (const float*)d_in[0];
  const float* sup_feat = (const float*)d_in[1];
  const float* pe       = (const float*)d_in[2];
  const float* fc_w     = (const float*)d_in[3];
  const float* fc_b     = (const float*)d_in[4];
  const float* wg_w     = (const float*)d_in[5];
  const float* wg_b     = (const float*)d_in[6];
  const float* wq_w     = (const float*)d_in[7];
  const float* wq_b     = (const float*)d_in[8];
  const float* wk_w     = (const float*)d_in[9];
  const float* wk_b     = (const float*)d_in[10];
  const float* wv_w     = (const float*)d_in[11];
  const float* wv_b     = (const float*)d_in[12];

  char* ws = (char*)d_ws;
  unsigned short* Xb  = (unsigned short*)(ws);              // [3072][1024]
  unsigned short* FCW = (unsigned short*)(ws + 6291456);
  unsigned short* WQB = (unsigned short*)(ws + 8388608);
  unsigned short* WKB = (unsigned short*)(ws + 10485760);
  unsigned short* WVB = (unsigned short*)(ws + 12582912);
  unsigned short* RS  = (unsigned short*)(ws + 14680064);   // [3072][1024] relu(fc) bf16
  unsigned short* QG  = (unsigned short*)(ws + 20971520);   // [16][2048][64]
  unsigned short* KG  = (unsigned short*)(ws + 25165824);   // [16][1024][64]
  unsigned short* SVT = (unsigned short*)(ws + 27262976);   // [16][64][1024]
  float*          Opart = (float*)(ws + 29360128);          // [4][2048][1024] f32
  float*          msb   = (float*)(ws + 62914560);          // [4][2048][16][2] f32

  cvt_all<<<7168, 256, 0, stream>>>(ref_feat, sup_feat, fc_w, wq_w, wk_w, wv_w,
                                    Xb, FCW, WQB, WKB, WVB);
  gemm_fc<<<dim3(24, 8), 256, 0, stream>>>(Xb, FCW, fc_b, RS);
  gemm_qkv<<<dim3(16, 8, 3), 256, 0, stream>>>(RS, WQB, WKB, WVB, wq_b, wk_b, QG, KG, SVT);
  pe_attn2<<<dim3(128, 4), 512, 0, stream>>>(pe, wg_w, wg_b, QG, KG, SVT, Opart, msb);
  combine<<<2048, 256, 0, stream>>>(Opart, msb, RS, wv_b, (float*)d_out);
}